// Round 1
// baseline (161.439 us; speedup 1.0000x reference)
//
#include <hip/hip_runtime.h>
#include <math.h>

// S4 layer: B=16, S=4096, D=256, N=16, then LayerNorm over D.
//   A_d = exp(-DT*|A|) (== 1.0f in fp32 for this data), v_t = (DT*Bm) @ u_t
//   h_t = clip(A_d*h_{t-1} + v_t)  -- clip never binds (|h| ~ 1e-4 << 10)
//   y_t = clip(h_t @ Cm^T + u_t*Dv); out = LN(y)
// Strategy: chunked parallel scan over S (chunks of 64), linearity exploited.
//   k_prep:      Bt[d][n] = DT*Bm[n][d]  (wave-uniform rows -> s_load path)
//   k_carry:     per-(b,chunk) local weighted sum -> carry[b][c][n] (+ optional v store)
//   k_chunkscan: sequential scan over 64 chunk carries -> Hstart[b][c][n]
//   k_out:       (re)build v, Kogge-Stone scan, add A^k*Hstart, y + LN, store.

#define NB 16
#define NS 4096
#define ND 256
#define NN 16
#define NL 64
#define NCH 64 // NS / NL
#define DTC 1e-4f
#define XSTR 129 // x half-tile LDS row stride (128 + 1 pad -> 2-way banks, free)
#define P2STR 17 // partial-v LDS stride
#define SCSTR 20 // scan LDS stride (80B rows: 16B-aligned for b128 broadcast reads)
#define NPOW (NL + 1)

__device__ __forceinline__ float clip10(float v) { return fminf(fmaxf(v, -10.f), 10.f); }

// Ptab[n][k] = A_d[n]^k for k = 0..64
__device__ __forceinline__ void build_ptab(const float* __restrict__ A, float* Ptab, int tid) {
  if (tid < NN) {
    float ad = expf(-DTC * fabsf(A[tid]));
    float p = 1.f;
    for (int k = 0; k < NPOW; ++k) { Ptab[tid * NPOW + k] = p; p *= ad; }
  }
}

// Per-thread partial v[t][n] (all 16 n) over d in [32dq,32dq+32) U [128+32dq, ...+32).
// t = tid & 63 (lane), dq = wave id (uniform -> Bt rows come from the scalar pipe).
// x staged in two 64x128 LDS half-tiles; 1 LDS b32 read per 16 FMAs.
__device__ __forceinline__ void compute_v(const float* __restrict__ xg,
                                          const float* __restrict__ Bt,
                                          float* xt, float acc[NN], int tid) {
  const int t = tid & 63;
  const int dq = __builtin_amdgcn_readfirstlane(tid >> 6);
#pragma unroll
  for (int n = 0; n < NN; ++n) acc[n] = 0.f;
  for (int h = 0; h < 2; ++h) {
    __syncthreads(); // protect xt from previous half's readers
    const float4* src4 = (const float4*)(xg + 128 * h);
#pragma unroll
    for (int k = 0; k < 8; ++k) {
      int fi4 = tid + 256 * k; // 2048 float4 = 64 rows x 128 floats
      int r = fi4 >> 5, q = fi4 & 31;
      float4 val = src4[r * 64 + q]; // global row stride = 64 float4
      float* dst = xt + r * XSTR + 4 * q;
      dst[0] = val.x; dst[1] = val.y; dst[2] = val.z; dst[3] = val.w;
    }
    __syncthreads();
    const int dl0 = 32 * dq;
    const float* xrow = xt + t * XSTR + dl0;
    const float* brow = Bt + (128 * h + dl0) * NN;
#pragma unroll 4
    for (int j = 0; j < 32; ++j) {
      float u = xrow[j];               // banks (t+j)%32: 2-way, free
      const float* bp = brow + j * NN; // wave-uniform address -> s_load
#pragma unroll
      for (int n = 0; n < NN; ++n) acc[n] = fmaf(u, bp[n], acc[n]);
    }
  }
}

__global__ __launch_bounds__(256, 2) void k_prep(const float* __restrict__ Bm,
                                                 float* __restrict__ Bt) {
  const int tid = threadIdx.x;
#pragma unroll
  for (int k = 0; k < 16; ++k) {
    int i = tid + 256 * k; // i = d*16 + n
    int d = i >> 4, n = i & 15;
    Bt[i] = DTC * Bm[n * ND + d];
  }
}

__global__ __launch_bounds__(256, 2) void k_carry(const float* __restrict__ x,
                                                  const float* __restrict__ A,
                                                  const float* __restrict__ Bt,
                                                  float* __restrict__ carry,
                                                  float* __restrict__ vws,
                                                  int use_vws) {
  __shared__ __align__(16) float xt[NL * XSTR];
  __shared__ __align__(16) float part2[4 * NL * P2STR];
  __shared__ float Ptab[NN * NPOW];
  __shared__ float part3[4][NN];
  const int tid = threadIdx.x;
  const int blk = blockIdx.x;
  const int b = blk >> 6, c = blk & 63;

  build_ptab(A, Ptab, tid);
  float acc[NN];
  const float* xg = x + ((size_t)(b * NS + c * NL)) * ND;
  compute_v(xg, Bt, xt, acc, tid);

  { // cross-wave (dq) reduction of v partials
    const int t = tid & 63, dq = tid >> 6;
    float* pp = part2 + dq * (NL * P2STR) + t * P2STR;
#pragma unroll
    for (int n = 0; n < NN; ++n) pp[n] = acc[n];
  }
  __syncthreads();
  float v4[4];
#pragma unroll
  for (int k = 0; k < 4; ++k) { // e = tid+256k <-> (t = e>>4, n = e&15)
    int e = tid + 256 * k;
    int o = (e >> 4) * P2STR + (e & 15);
    v4[k] = (part2[o] + part2[NL * P2STR + o]) +
            (part2[2 * NL * P2STR + o] + part2[3 * NL * P2STR + o]);
  }
  if (use_vws) {
    float* vp = vws + (size_t)blk * (NL * NN);
#pragma unroll
    for (int k = 0; k < 4; ++k) vp[tid + 256 * k] = v4[k];
  }
  // carry[n] = sum_t A^(63-t) * v[t][n]
  const int t0 = tid >> 4, n = tid & 15;
  float val = 0.f;
#pragma unroll
  for (int k = 0; k < 4; ++k)
    val = fmaf(Ptab[n * NPOW + 63 - (t0 + 16 * k)], v4[k], val);
  val += __shfl_xor(val, 16);
  val += __shfl_xor(val, 32); // every lane now holds sum over its n-group
  const int w = tid >> 6, lane = tid & 63;
  if (lane < NN) part3[w][lane] = val;
  __syncthreads();
  if (tid < NN) {
    float s = (part3[0][tid] + part3[1][tid]) + (part3[2][tid] + part3[3][tid]);
    carry[(size_t)(b * NCH + c) * NN + tid] = s;
  }
}

__global__ __launch_bounds__(256, 1) void k_chunkscan(const float* __restrict__ A,
                                                      const float* __restrict__ carry,
                                                      float* __restrict__ Hstart) {
  const int tid = threadIdx.x; // 256 = 16 b x 16 n
  const int b = tid >> 4, n = tid & 15;
  float ad = expf(-DTC * fabsf(A[n]));
  float a64 = ad;
#pragma unroll
  for (int k = 0; k < 6; ++k) a64 *= a64; // ad^64
  const float* cp = carry + (size_t)b * (NCH * NN) + n;
  float* hp = Hstart + (size_t)b * (NCH * NN) + n;
  float H = 0.f;
#pragma unroll 8
  for (int c = 0; c < NCH; ++c) {
    hp[c * NN] = H; // state ENTERING chunk c (exclusive scan)
    H = fmaf(a64, H, cp[c * NN]);
  }
}

template <int LOADV>
__global__ __launch_bounds__(256, 2) void k_out(const float* __restrict__ x,
                                                const float* __restrict__ A,
                                                const float* __restrict__ Bt,
                                                const float* __restrict__ Cm,
                                                const float* __restrict__ Dv,
                                                const float* __restrict__ gamma,
                                                const float* __restrict__ beta,
                                                const float* __restrict__ Hstart,
                                                const float* __restrict__ vws,
                                                float* __restrict__ out) {
  __shared__ __align__(16) float scan[NL * SCSTR];
  __shared__ float Ptab[NN * NPOW];
  __shared__ float hst[NN];
  const int tid = threadIdx.x;
  const int blk = blockIdx.x;
  const int b = blk >> 6, c = blk & 63;

  build_ptab(A, Ptab, tid);
  if (tid < NN) hst[tid] = Hstart[(size_t)(b * NCH + c) * NN + tid];
  const size_t rowbase = ((size_t)(b * NS + c * NL)) * ND;

  if constexpr (LOADV) {
    const float* vp = vws + (size_t)blk * (NL * NN);
#pragma unroll
    for (int k = 0; k < 4; ++k) {
      int e = tid + 256 * k;
      scan[(e >> 4) * SCSTR + (e & 15)] = vp[e];
    }
  } else {
    __shared__ __align__(16) float xt[NL * XSTR];
    __shared__ __align__(16) float part2[4 * NL * P2STR];
    float acc[NN];
    compute_v(x + rowbase, Bt, xt, acc, tid);
    {
      const int t = tid & 63, dq = tid >> 6;
      float* pp = part2 + dq * (NL * P2STR) + t * P2STR;
#pragma unroll
      for (int n = 0; n < NN; ++n) pp[n] = acc[n];
    }
    __syncthreads();
#pragma unroll
    for (int k = 0; k < 4; ++k) {
      int e = tid + 256 * k;
      int o = (e >> 4) * P2STR + (e & 15);
      scan[(e >> 4) * SCSTR + (e & 15)] =
          (part2[o] + part2[NL * P2STR + o]) +
          (part2[2 * NL * P2STR + o] + part2[3 * NL * P2STR + o]);
    }
  }
  __syncthreads();

  // Kogge-Stone inclusive scan over t (per n) with decay weights A^s
#pragma unroll
  for (int s = 1; s <= 32; s <<= 1) {
    float tmp[4];
#pragma unroll
    for (int k = 0; k < 4; ++k) {
      int e = tid + 256 * k;
      int tt = e >> 4, n = e & 15;
      tmp[k] = (tt >= s) ? Ptab[n * NPOW + s] * scan[(tt - s) * SCSTR + n] : 0.f;
    }
    __syncthreads();
#pragma unroll
    for (int k = 0; k < 4; ++k) {
      int e = tid + 256 * k;
      scan[(e >> 4) * SCSTR + (e & 15)] += tmp[k];
    }
    __syncthreads();
  }
  // h_t = A^(tl+1) * Hstart + hloc_t, clip (no-op on this data, matches ref)
#pragma unroll
  for (int k = 0; k < 4; ++k) {
    int e = tid + 256 * k;
    int tt = e >> 4, n = e & 15;
    float hv = fmaf(Ptab[n * NPOW + tt + 1], hst[n], scan[tt * SCSTR + n]);
    scan[tt * SCSTR + n] = clip10(hv);
  }
  __syncthreads();

  // y = h @ Cm^T + u*Dv, clip, LayerNorm over d (d = lane dim -> wave butterfly)
  const int l = tid & 63;
  const int w = __builtin_amdgcn_readfirstlane(tid >> 6);
  float cm[4][NN]; // Cm rows for this lane's 4 d's, hoisted (fixed per lane)
  const float4* Cm4 = (const float4*)Cm;
#pragma unroll
  for (int j = 0; j < 4; ++j)
#pragma unroll
    for (int q = 0; q < 4; ++q) {
      float4 cv = Cm4[(4 * l + j) * 4 + q];
      cm[j][4 * q + 0] = cv.x; cm[j][4 * q + 1] = cv.y;
      cm[j][4 * q + 2] = cv.z; cm[j][4 * q + 3] = cv.w;
    }
  const float4 dv = ((const float4*)Dv)[l];
  const float4 gm = ((const float4*)gamma)[l];
  const float4 bet = ((const float4*)beta)[l];

#pragma unroll 1
  for (int it = 0; it < 16; ++it) { // wave w handles tokens [16w, 16w+16)
    const int t = 16 * w + it;
    const float4 xv = *(const float4*)(x + rowbase + (size_t)t * ND + 4 * l);
    const float* hrow = scan + t * SCSTR; // 16B-aligned, broadcast b128 reads
    float y0 = xv.x * dv.x, y1 = xv.y * dv.y, y2 = xv.z * dv.z, y3 = xv.w * dv.w;
#pragma unroll
    for (int nn = 0; nn < NN; ++nn) {
      float hv = hrow[nn];
      y0 = fmaf(hv, cm[0][nn], y0);
      y1 = fmaf(hv, cm[1][nn], y1);
      y2 = fmaf(hv, cm[2][nn], y2);
      y3 = fmaf(hv, cm[3][nn], y3);
    }
    y0 = clip10(y0); y1 = clip10(y1); y2 = clip10(y2); y3 = clip10(y3);
    float s1 = (y0 + y1) + (y2 + y3);
    float s2 = fmaf(y0, y0, fmaf(y1, y1, fmaf(y2, y2, y3 * y3)));
#pragma unroll
    for (int off = 32; off; off >>= 1) {
      s1 += __shfl_xor(s1, off);
      s2 += __shfl_xor(s2, off);
    }
    const float mu = s1 * (1.f / 256.f);
    const float var = fmaf(-mu, mu, s2 * (1.f / 256.f));
    const float rs = rsqrtf(var + 1e-5f);
    float4 o;
    o.x = fmaf((y0 - mu) * rs, gm.x, bet.x);
    o.y = fmaf((y1 - mu) * rs, gm.y, bet.y);
    o.z = fmaf((y2 - mu) * rs, gm.z, bet.z);
    o.w = fmaf((y3 - mu) * rs, gm.w, bet.w);
    *(float4*)(out + rowbase + (size_t)t * ND + 4 * l) = o;
  }
}

extern "C" void kernel_launch(void* const* d_in, const int* in_sizes, int n_in,
                              void* d_out, int out_size, void* d_ws, size_t ws_size,
                              hipStream_t stream) {
  const float* x = (const float*)d_in[0];
  const float* A = (const float*)d_in[1];
  const float* Bm = (const float*)d_in[2];
  const float* Cm = (const float*)d_in[3];
  const float* Dv = (const float*)d_in[4];
  const float* gamma = (const float*)d_in[5];
  const float* beta = (const float*)d_in[6];
  float* out = (float*)d_out;
  char* ws = (char*)d_ws;

  float* Bt = (float*)ws;                         // 16 KiB
  float* carry = (float*)(ws + 16384);            // 64 KiB
  float* Hstart = (float*)(ws + 16384 + 65536);   // 64 KiB
  float* vws = (float*)(ws + 147456);             // optional 4 MiB
  const size_t VWS_BYTES = (size_t)NB * NS * NN * sizeof(float);
  const int use_vws = (ws_size >= (size_t)147456 + VWS_BYTES) ? 1 : 0;

  k_prep<<<dim3(1), dim3(256), 0, stream>>>(Bm, Bt);
  k_carry<<<dim3(NB * NCH), dim3(256), 0, stream>>>(x, A, Bt, carry, vws, use_vws);
  k_chunkscan<<<dim3(1), dim3(256), 0, stream>>>(A, carry, Hstart);
  if (use_vws)
    k_out<1><<<dim3(NB * NCH), dim3(256), 0, stream>>>(x, A, Bt, Cm, Dv, gamma, beta,
                                                       Hstart, vws, out);
  else
    k_out<0><<<dim3(NB * NCH), dim3(256), 0, stream>>>(x, A, Bt, Cm, Dv, gamma, beta,
                                                       Hstart, vws, out);
}